// Round 7
// baseline (185.090 us; speedup 1.0000x reference)
//
#include <hip/hip_runtime.h>
#include <hip/hip_bf16.h>
#include <stdint.h>

typedef __attribute__((ext_vector_type(8))) short short8;
typedef __attribute__((ext_vector_type(4))) float f32x4;
typedef __attribute__((ext_vector_type(4))) unsigned short ushort4v;

#define MFMA16(a, b, c) __builtin_amdgcn_mfma_f32_16x16x32_bf16((a), (b), (c), 0, 0, 0)

// sizes: B=16, C=256, N=1024 (32x32), HEADS=4, DHEAD=64, HID=256, OTOT=768

__device__ __forceinline__ ushort f2bf(float f) {
  union { float f; unsigned u; } x; x.f = f;
  unsigned r = x.u + 0x7FFFu + ((x.u >> 16) & 1u);
  return (ushort)(r >> 16);
}

__device__ __forceinline__ short8 ld8(const ushort* p) {
  return *reinterpret_cast<const short8*>(p);
}

// async global->LDS, 16B per lane; LDS dest = wave-uniform base + lane*16 (m104);
// global src is per-lane (m173).
__device__ __forceinline__ void gll16(const void* g, void* l) {
  __builtin_amdgcn_global_load_lds(
      reinterpret_cast<const __attribute__((address_space(1))) unsigned int*>(
          reinterpret_cast<uintptr_t>(g)),
      reinterpret_cast<__attribute__((address_space(3))) unsigned int*>(
          reinterpret_cast<uintptr_t>(l)),
      16, 0, 0);
}

// Stage one 32 KB tile (128 rows x 256 B) out of a global panel whose rows are
// 512 B apart (c-half of a [n][256c] bf16 panel). Inverse swizzle
// (16B-slot ^= row&7) pre-applied to the GLOBAL source; LDS stays linear.
// goff/ldsw precomputed per-thread (see callers). 512 threads, 4 calls.
__device__ __forceinline__ void stage_tile32(const char* gbase, char* ldsbase,
                                             int goff, int ldsw) {
#pragma unroll
  for (int c = 0; c < 4; ++c)
    gll16(gbase + c * 16384 + goff, ldsbase + c * 8192 + ldsw);
}

// ---------------- kernel 0: transpose+convert x,y (b,c,n)f32 -> (b,n,c)bf16,
// vectorized (float4 in, ushort4 out, transposed LDS staging).
// Tail blocks (tile >= 2048): weight conversion, float4-vectorized.
__global__ __launch_bounds__(256) void k_tcvt(const float* __restrict__ x,
    const float* __restrict__ y, ushort* __restrict__ xbt, ushort* __restrict__ ybt,
    const float* __restrict__ wqkv, const float* __restrict__ wout,
    ushort* __restrict__ wqkvb, ushort* __restrict__ woutb) {
  int tile = blockIdx.x;
  if (tile >= 2048) {   // weight-conversion blocks (64), float4 grid-stride
    const int t1 = 49152;           // 768*256/4
    const int tot = t1 + 16384;     // + 256*256/4
    for (int i = (tile - 2048) * 256 + threadIdx.x; i < tot; i += 64 * 256) {
      if (i < t1) {
        float4 v = reinterpret_cast<const float4*>(wqkv)[i];
        ushort4v u = {f2bf(v.x), f2bf(v.y), f2bf(v.z), f2bf(v.w)};
        reinterpret_cast<ushort4v*>(wqkvb)[i] = u;
      } else {
        int j = i - t1;
        float4 v = reinterpret_cast<const float4*>(wout)[j];
        ushort4v u = {f2bf(v.x), f2bf(v.y), f2bf(v.z), f2bf(v.w)};
        reinterpret_cast<ushort4v*>(woutb)[j] = u;
      }
    }
    return;
  }
  const float* src; ushort* dst;
  if (tile >= 1024) { tile -= 1024; src = y; dst = ybt; }
  else { src = x; dst = xbt; }
  int b = tile >> 6;
  int c0 = ((tile >> 4) & 3) << 6;
  int n0 = (tile & 15) << 6;
  __shared__ ushort ldsT[64][72];   // [n][c], pad to 72 (144B rows, 8B-aligned)
  int tid = threadIdx.x;
  const float* sb = src + ((size_t)b << 18);
  // phase 1: float4 loads (4 passes x 16 c-rows x 16 float4), scatter to ldsT
  int cc = tid >> 4, n4 = tid & 15;
#pragma unroll
  for (int s = 0; s < 4; ++s) {
    int c = cc + s * 16;
    float4 v = *reinterpret_cast<const float4*>(sb + (size_t)(c0 + c) * 1024 + n0 + n4 * 4);
    ldsT[n4 * 4 + 0][c] = f2bf(v.x);
    ldsT[n4 * 4 + 1][c] = f2bf(v.y);
    ldsT[n4 * 4 + 2][c] = f2bf(v.z);
    ldsT[n4 * 4 + 3][c] = f2bf(v.w);
  }
  __syncthreads();
  // phase 2: ushort4 reads along c, wide global stores to [n][256] layout
  ushort* db = dst + ((size_t)b << 18);
  int nn = tid >> 4, c4 = tid & 15;
#pragma unroll
  for (int s = 0; s < 4; ++s) {
    int n = nn + s * 16;
    ushort4v u = *reinterpret_cast<const ushort4v*>(&ldsT[n][c4 * 4]);
    *reinterpret_cast<ushort4v*>(db + (size_t)(n0 + n) * 256 + c0 + c4 * 4) = u;
  }
}

// ---------------- kernel 1: QKV projection GEMM with fused l2norm + transpose.
// flat grid 384 = 24 o-tiles x 16 b, XCD-swizzled (48/XCD = 2 batches' panels,
// L2-resident). 512 thr = 8 waves. Block: 32o x 1024n (norm block-local).
// B staged via global_load_lds in 128n x 128c (32 KB) double-buffered tiles
// (16 tiles: 8 n-chunks x 2 c-halves) -> 64 KB LDS -> 2 blocks/CU.
// A read per-tile from the L1-resident 16 KB weight panel (keeps VGPR <= 128).
// q,k: normalized (SCALE folded into q), stored [hb][n][64] packed ushort4.
// v: stored [b][256][1024] bf16.
__global__ __launch_bounds__(512, 4) void k_qkv(const ushort* __restrict__ wqkvb,
    const ushort* __restrict__ xbt, const ushort* __restrict__ ybt,
    ushort* __restrict__ qt, ushort* __restrict__ kt, ushort* __restrict__ vbuf) {
  int bid = blockIdx.x;
  int lid = (bid & 7) * 48 + (bid >> 3);
  int ox = lid % 24;
  int b = lid / 24;
  int o0 = ox * 32;
  const ushort* Bsrc = (o0 < 256) ? xbt : ybt;   // q from x; k,v from y
  const char* Bm = (const char*)(Bsrc + ((size_t)b << 18));   // [1024][256] bf16
  int tid = threadIdx.x;
  int l = tid & 63, w = tid >> 6;
  int r = l & 15, g = l >> 4;

  __shared__ __align__(16) char Bt[2][32768];
  __shared__ float snorm[8][32];
  __shared__ float fs[32];

  const ushort* Ab = wqkvb + (size_t)(o0 + r) * 256 + g * 8;

  // staging geometry: tile rows are 256 B; global row stride 512 B
  int Lb = tid * 16;
  int trow = Lb >> 8;                              // 0..31 within 8 KB call
  int goff = trow * 512 + ((Lb & 255) ^ ((trow & 7) << 4));
  int ldsw = w * 1024;                             // wave-uniform dest base

  f32x4 acc[2][8];
#pragma unroll
  for (int i = 0; i < 2; ++i)
#pragma unroll
    for (int j = 0; j < 8; ++j) acc[i][j] = (f32x4){0.f, 0.f, 0.f, 0.f};

  stage_tile32(Bm, &Bt[0][0], goff, ldsw);
  __syncthreads();

  int rr = w * 16 + r;               // tile row this lane reads (0..127)
  int sw = (r & 7) << 4;
  for (int t = 0; t < 16; ++t) {     // t = nchunk*2 + chalf
    int cur = t & 1;
    if (t < 15) {
      int t1 = t + 1;
      stage_tile32(Bm + (size_t)(t1 >> 1) * 65536 + (t1 & 1) * 256,
                   &Bt[cur ^ 1][0], goff, ldsw);
    }
    const char* Bc = &Bt[cur][0];
    int nchunk = t >> 1, chalf = t & 1;
#pragma unroll
    for (int ks4 = 0; ks4 < 4; ++ks4) {
      int ks = chalf * 4 + ks4;
      short8 a0 = ld8(Ab + ks * 32);
      short8 a1 = ld8(Ab + 4096 + ks * 32);
      short8 bv = *reinterpret_cast<const short8*>(Bc + rr * 256 + ((ks4 * 64 + g * 16) ^ sw));
      acc[0][nchunk] = MFMA16(a0, bv, acc[0][nchunk]);
      acc[1][nchunk] = MFMA16(a1, bv, acc[1][nchunk]);
    }
    __syncthreads();
  }

  if (o0 < 512) {
    // ---- block-local row sum-of-squares (rows complete: full n in block)
    float ss[2][4];
#pragma unroll
    for (int mf = 0; mf < 2; ++mf)
#pragma unroll
      for (int reg = 0; reg < 4; ++reg) {
        float s = 0.f;
#pragma unroll
        for (int nt = 0; nt < 8; ++nt) { float v = acc[mf][nt][reg]; s += v * v; }
#pragma unroll
        for (int m = 1; m < 16; m <<= 1) s += __shfl_xor(s, m);
        ss[mf][reg] = s;
      }
    if (r == 0) {
#pragma unroll
      for (int mf = 0; mf < 2; ++mf)
#pragma unroll
        for (int reg = 0; reg < 4; ++reg)
          snorm[w][mf * 16 + g * 4 + reg] = ss[mf][reg];
    }
    __syncthreads();
    if (tid < 32) {
      float s = 0.f;
#pragma unroll
      for (int w2 = 0; w2 < 8; ++w2) s += snorm[w2][tid];
      fs[tid] = ((o0 < 256) ? 10.0f : 1.0f) / fmaxf(sqrtf(s), 1e-12f);
    }
    __syncthreads();
    float fr[2][4];
#pragma unroll
    for (int mf = 0; mf < 2; ++mf)
#pragma unroll
      for (int reg = 0; reg < 4; ++reg) fr[mf][reg] = fs[mf * 16 + g * 4 + reg];
    // ---- normalize in-register, pack 4 consecutive d, store [hb][n][64]
    int od = (o0 < 256) ? o0 : o0 - 256;      // 0..255
    int hh = od >> 6, d0 = od & 63;           // d0 in {0,32}
    ushort* dst = ((o0 < 256) ? qt : kt) + (((size_t)(b * 4 + hh)) << 16);
#pragma unroll
    for (int mf = 0; mf < 2; ++mf)
#pragma unroll
      for (int nt = 0; nt < 8; ++nt) {
        int n = nt * 128 + w * 16 + r;
        ushort4v u;
#pragma unroll
        for (int reg = 0; reg < 4; ++reg) u[reg] = f2bf(acc[mf][nt][reg] * fr[mf][reg]);
        *reinterpret_cast<ushort4v*>(dst + (size_t)n * 64 + d0 + mf * 16 + g * 4) = u;
      }
  } else {
    // ---- v: store [b][256][1024] bf16 (16-lane-contiguous 32B segments)
#pragma unroll
    for (int mf = 0; mf < 2; ++mf) {
      int ob = o0 - 512 + mf * 16 + g * 4;
#pragma unroll
      for (int nt = 0; nt < 8; ++nt) {
        int n = nt * 128 + w * 16 + r;
#pragma unroll
        for (int reg = 0; reg < 4; ++reg)
          vbuf[(((size_t)b * 256 + ob + reg) << 10) + n] = f2bf(acc[mf][nt][reg]);
      }
    }
  }
}

// ---------------- kernel 2: fused attention, LDS-staged K/V (double-buffered),
// no-max softmax, unnormalized accumulate.  (unchanged from round 6)
// grid dim3(64 hb, 8 it): bid%8 = hb%8 -> all i-tiles of 8 hb share an XCD
// (2 MB K/V, L2-resident). 512 thr = 8 waves; wave owns 16 q-rows.
// LDS 48 KB -> 2 blocks/CU (16 waves/CU).
__global__ __launch_bounds__(512, 4) void k_attn(const ushort* __restrict__ qt,
    const ushort* __restrict__ kt, const ushort* __restrict__ vbuf,
    ushort* __restrict__ aot) {
  int hb = blockIdx.x;            // b*4 + h
  int it = blockIdx.y;            // 0..7
  int h = hb & 3, b = hb >> 2;
  int tid = threadIdx.x;
  int l = tid & 63, w = tid >> 6;
  int r = l & 15, g = l >> 4;
  size_t ho = ((size_t)hb) << 16;
  const ushort* Q = qt + ho;      // [n][64]
  const char* Kg = (const char*)(kt + ho);                                       // [n][64]
  const char* Vg = (const char*)(vbuf + ((size_t)b << 18) + ((size_t)h << 16));  // [d][n]
  int i0 = it * 128 + w * 16;

  __shared__ __align__(16) ushort Kb[2][4096];   // 64 rows x 64 cols, XOR-swizzled
  __shared__ __align__(16) ushort Vb[2][4096];
  __shared__ __align__(16) ushort plds[8][1024]; // per-wave 16x64 P, XOR-swizzled

  // staging geometry: tile = 8 KB; wave w moves bytes [w*1024, w*1024+1024)
  int L = w * 1024 + l * 16;            // linear LDS byte offset in tile
  int srow = L >> 7;                    // tile row (64 x 128B rows)
  int swz = (srow & 7) << 4;
  int ksrc = L ^ swz;                   // K: contiguous tile, involutive swizzle
  int vsrc_col = (L & 127) ^ swz;       // V: per-row 128B slice of [d][1024]

  short8 qa[2];
#pragma unroll
  for (int ks = 0; ks < 2; ++ks)
    qa[ks] = ld8(Q + (size_t)(i0 + r) * 64 + ks * 32 + g * 8);

  f32x4 oacc[4];
  float rsum[4];
#pragma unroll
  for (int j = 0; j < 4; ++j) { oacc[j] = (f32x4){0.f, 0.f, 0.f, 0.f}; rsum[j] = 0.f; }

#define STAGE(buf, j0v) do { \
    gll16(Kg + (j0v) * 128 + ksrc, (char*)&Kb[buf][0] + w * 1024); \
    gll16(Vg + (size_t)srow * 2048 + (j0v) * 2 + vsrc_col, (char*)&Vb[buf][0] + w * 1024); \
  } while (0)

  STAGE(0, 0);
  __syncthreads();   // drains vmcnt before reads

  char* plc = (char*)plds[w];
  for (int t = 0; t < 16; ++t) {
    int cur = t & 1;
    if (t < 15) STAGE(cur ^ 1, (t + 1) * 64);
    const char* Kc = (const char*)&Kb[cur][0];
    const char* Vc = (const char*)&Vb[cur][0];
    // ---- QK^T on this 64-col tile
    f32x4 sacc[4];
#pragma unroll
    for (int nf = 0; nf < 4; ++nf) sacc[nf] = (f32x4){0.f, 0.f, 0.f, 0.f};
#pragma unroll
    for (int nf = 0; nf < 4; ++nf) {
      int row = nf * 16 + r;
      int sw = (row & 7) << 4;
      short8 k0 = *reinterpret_cast<const short8*>(Kc + ((row * 128 + g * 16) ^ sw));
      short8 k1 = *reinterpret_cast<const short8*>(Kc + ((row * 128 + 64 + g * 16) ^ sw));
      sacc[nf] = MFMA16(qa[0], k0, sacc[nf]);
      sacc[nf] = MFMA16(qa[1], k1, sacc[nf]);
    }
    // ---- P = exp(S); row sums; P -> per-wave LDS (swizzled; bf16 truncation:
    // bias is common-mode between numerator and row-sum denominator)
#pragma unroll
    for (int nf = 0; nf < 4; ++nf)
#pragma unroll
      for (int reg = 0; reg < 4; ++reg) {
        float p = __expf(sacc[nf][reg]);
        rsum[reg] += p;
        union { float f; unsigned u; } cv; cv.f = p;
        int row = g * 4 + reg;
        int xorv = ((row ^ (row >> 3)) & 7) << 4;
        int byteo = row * 128 + (((nf * 16 + r) * 2) ^ xorv);
        *(ushort*)(plc + byteo) = (ushort)(cv.u >> 16);
      }
    // read back as A-fragments
    short8 pa[2];
#pragma unroll
    for (int ks = 0; ks < 2; ++ks) {
      int xorv = (r ^ (r >> 3)) & 7;
      int blk = (ks * 4 + g) ^ xorv;
      pa[ks] = *reinterpret_cast<const short8*>(plc + r * 128 + blk * 16);
    }
    // ---- O += P * V^T
#pragma unroll
    for (int df = 0; df < 4; ++df) {
      int row = df * 16 + r;
      int sw = (row & 7) << 4;
#pragma unroll
      for (int ks = 0; ks < 2; ++ks) {
        short8 vf = *reinterpret_cast<const short8*>(Vc + ((row * 128 + ks * 64 + g * 16) ^ sw));
        oacc[df] = MFMA16(pa[ks], vf, oacc[df]);
      }
    }
    __syncthreads();  // next tile staged (vmcnt drained) + buf reuse safe
  }
#undef STAGE

  // finalize: divide by row sums, store [n][hid] bf16
#pragma unroll
  for (int reg = 0; reg < 4; ++reg) {
    float s = rsum[reg];
#pragma unroll
    for (int m = 1; m < 16; m <<= 1) s += __shfl_xor(s, m);
    rsum[reg] = 1.0f / s;
  }
#pragma unroll
  for (int df = 0; df < 4; ++df)
#pragma unroll
    for (int reg = 0; reg < 4; ++reg) {
      int i = i0 + g * 4 + reg;
      int d = df * 16 + r;
      float vo = oacc[df][reg] * rsum[reg];
      aot[((size_t)b << 18) + (size_t)i * 256 + h * 64 + d] = f2bf(vo);
    }
}

// ---------------- kernel 3: output projection + bias, LDS-staged B.
// flat grid 512 = 8 o-tiles x 4 n-quarters x 16 b, XCD-swizzled (64/XCD =
// 2 batches' aot panels, 1 MB L2-resident). 512 thr = 8 waves.
// Block: 32o x 256n; 4 staged tiles (128n x 128c, 32 KB) double-buffered
// -> 64 KB LDS -> 2 blocks/CU (512 blocks = perfect fill).
__global__ __launch_bounds__(512, 4) void k_out(const ushort* __restrict__ woutb,
    const ushort* __restrict__ aot, const float* __restrict__ bout,
    float* __restrict__ out) {
  int bid = blockIdx.x;
  int lid = (bid & 7) * 64 + (bid >> 3);
  int ox = lid & 7;
  int t2 = lid >> 3;
  int nq = t2 & 3;
  int b = t2 >> 2;
  int o0 = ox * 32;
  int tid = threadIdx.x, l = tid & 63, w = tid >> 6, r = l & 15, g = l >> 4;
  const char* Bm = (const char*)(aot + ((size_t)b << 18) + ((size_t)nq << 16));  // [256][256] bf16

  __shared__ __align__(16) char Bt[2][32768];

  const ushort* Ab = woutb + (size_t)(o0 + r) * 256 + g * 8;

  int Lb = tid * 16;
  int trow = Lb >> 8;
  int goff = trow * 512 + ((Lb & 255) ^ ((trow & 7) << 4));
  int ldsw = w * 1024;

  f32x4 acc[2][2];
#pragma unroll
  for (int i = 0; i < 2; ++i)
#pragma unroll
    for (int j = 0; j < 2; ++j) acc[i][j] = (f32x4){0.f, 0.f, 0.f, 0.f};

  stage_tile32(Bm, &Bt[0][0], goff, ldsw);
  __syncthreads();

  int rr = w * 16 + r;
  int sw = (r & 7) << 4;
  for (int t = 0; t < 4; ++t) {      // t = nchunk*2 + chalf
    int cur = t & 1;
    if (t < 3) {
      int t1 = t + 1;
      stage_tile32(Bm + (size_t)(t1 >> 1) * 65536 + (t1 & 1) * 256,
                   &Bt[cur ^ 1][0], goff, ldsw);
    }
    const char* Bc = &Bt[cur][0];
    int nchunk = t >> 1, chalf = t & 1;
#pragma unroll
    for (int ks4 = 0; ks4 < 4; ++ks4) {
      int ks = chalf * 4 + ks4;
      short8 a0 = ld8(Ab + ks * 32);
      short8 a1 = ld8(Ab + 4096 + ks * 32);
      short8 bv = *reinterpret_cast<const short8*>(Bc + rr * 256 + ((ks4 * 64 + g * 16) ^ sw));
      acc[0][nchunk] = MFMA16(a0, bv, acc[0][nchunk]);
      acc[1][nchunk] = MFMA16(a1, bv, acc[1][nchunk]);
    }
    __syncthreads();
  }

  float bias[2][4];
#pragma unroll
  for (int mf = 0; mf < 2; ++mf)
#pragma unroll
    for (int reg = 0; reg < 4; ++reg) bias[mf][reg] = bout[o0 + mf * 16 + g * 4 + reg];
#pragma unroll
  for (int mf = 0; mf < 2; ++mf)
#pragma unroll
    for (int nt = 0; nt < 2; ++nt)
#pragma unroll
      for (int reg = 0; reg < 4; ++reg) {
        size_t o = (size_t)(b * 256 + o0 + mf * 16 + g * 4 + reg);
        int n = nq * 256 + nt * 128 + w * 16 + r;
        out[(o << 10) + n] = acc[mf][nt][reg] + bias[mf][reg];
      }
}

extern "C" void kernel_launch(void* const* d_in, const int* in_sizes, int n_in,
                              void* d_out, int out_size, void* d_ws, size_t ws_size,
                              hipStream_t stream) {
  const float* x     = (const float*)d_in[0];
  const float* y     = (const float*)d_in[1];
  const float* wqkv  = (const float*)d_in[2];
  const float* wout  = (const float*)d_in[3];
  const float* bout  = (const float*)d_in[4];
  float* out = (float*)d_out;
  char* ws = (char*)d_ws;

  // Workspace (~40.6 MB). Aliases: xbt dead after k_qkv -> aot reuses it.
  ushort* xbt   = (ushort*)(ws + 0ull);          // 8 MiB
  ushort* aot   = (ushort*)(ws + 0ull);          //   (written by k_attn)
  ushort* ybt   = (ushort*)(ws + 8388608ull);    // 8 MiB
  ushort* qt    = (ushort*)(ws + 16777216ull);   // 8 MiB
  ushort* kt    = (ushort*)(ws + 25165824ull);   // 8 MiB
  ushort* vbuf  = (ushort*)(ws + 33554432ull);   // 8 MiB
  ushort* wqkvb = (ushort*)(ws + 41943040ull);   // 384 KiB
  ushort* woutb = (ushort*)(ws + 42336256ull);   // 128 KiB

  k_tcvt<<<2112, 256, 0, stream>>>(x, y, xbt, ybt, wqkv, wout, wqkvb, woutb);
  k_qkv<<<384, 512, 0, stream>>>(wqkvb, xbt, ybt, qt, kt, vbuf);
  k_attn<<<dim3(64, 8), 512, 0, stream>>>(qt, kt, vbuf, aot);
  k_out<<<512, 512, 0, stream>>>(woutb, aot, bout, out);
}

// Round 8
// 157.147 us; speedup vs baseline: 1.1778x; 1.1778x over previous
//
#include <hip/hip_runtime.h>
#include <hip/hip_bf16.h>
#include <stdint.h>

typedef __attribute__((ext_vector_type(8))) short short8;
typedef __attribute__((ext_vector_type(4))) float f32x4;
typedef __attribute__((ext_vector_type(4))) unsigned short ushort4v;

#define MFMA16(a, b, c) __builtin_amdgcn_mfma_f32_16x16x32_bf16((a), (b), (c), 0, 0, 0)

// sizes: B=16, C=256, N=1024 (32x32), HEADS=4, DHEAD=64, HID=256, OTOT=768

__device__ __forceinline__ ushort f2bf(float f) {
  union { float f; unsigned u; } x; x.f = f;
  unsigned r = x.u + 0x7FFFu + ((x.u >> 16) & 1u);
  return (ushort)(r >> 16);
}

__device__ __forceinline__ short8 ld8(const ushort* p) {
  return *reinterpret_cast<const short8*>(p);
}

// async global->LDS, 16B per lane; LDS dest = wave-uniform base + lane*16 (m104);
// global src is per-lane (m173).
__device__ __forceinline__ void gll16(const void* g, void* l) {
  __builtin_amdgcn_global_load_lds(
      reinterpret_cast<const __attribute__((address_space(1))) unsigned int*>(
          reinterpret_cast<uintptr_t>(g)),
      reinterpret_cast<__attribute__((address_space(3))) unsigned int*>(
          reinterpret_cast<uintptr_t>(l)),
      16, 0, 0);
}

// Stage one 64 KB tile (128 rows x 512 B) with involutive swizzle
// (16B-slot ^= row&7) pre-applied to the GLOBAL source; LDS stays linear.
// 512 threads x 8 calls x 16 B. goff/ldsw precomputed per-thread.
__device__ __forceinline__ void stage_tile(const char* gbase, char* ldsbase,
                                           int goff, int ldsw) {
#pragma unroll
  for (int c = 0; c < 8; ++c)
    gll16(gbase + c * 8192 + goff, ldsbase + c * 8192 + ldsw);
}

// ---------------- kernel 0: transpose+convert x,y (b,c,n)f32 -> (b,n,c)bf16,
// vectorized (float4 in, ushort4 out, transposed LDS staging).
// Tail blocks (tile >= 2048): weight conversion, float4-vectorized.
__global__ __launch_bounds__(256) void k_tcvt(const float* __restrict__ x,
    const float* __restrict__ y, ushort* __restrict__ xbt, ushort* __restrict__ ybt,
    const float* __restrict__ wqkv, const float* __restrict__ wout,
    ushort* __restrict__ wqkvb, ushort* __restrict__ woutb) {
  int tile = blockIdx.x;
  if (tile >= 2048) {   // weight-conversion blocks (64), float4 grid-stride
    const int t1 = 49152;           // 768*256/4
    const int tot = t1 + 16384;     // + 256*256/4
    for (int i = (tile - 2048) * 256 + threadIdx.x; i < tot; i += 64 * 256) {
      if (i < t1) {
        float4 v = reinterpret_cast<const float4*>(wqkv)[i];
        ushort4v u = {f2bf(v.x), f2bf(v.y), f2bf(v.z), f2bf(v.w)};
        reinterpret_cast<ushort4v*>(wqkvb)[i] = u;
      } else {
        int j = i - t1;
        float4 v = reinterpret_cast<const float4*>(wout)[j];
        ushort4v u = {f2bf(v.x), f2bf(v.y), f2bf(v.z), f2bf(v.w)};
        reinterpret_cast<ushort4v*>(woutb)[j] = u;
      }
    }
    return;
  }
  const float* src; ushort* dst;
  if (tile >= 1024) { tile -= 1024; src = y; dst = ybt; }
  else { src = x; dst = xbt; }
  int b = tile >> 6;
  int c0 = ((tile >> 4) & 3) << 6;
  int n0 = (tile & 15) << 6;
  __shared__ ushort ldsT[64][72];   // [n][c], pad to 72
  int tid = threadIdx.x;
  const float* sb = src + ((size_t)b << 18);
  int cc = tid >> 4, n4 = tid & 15;
#pragma unroll
  for (int s = 0; s < 4; ++s) {
    int c = cc + s * 16;
    float4 v = *reinterpret_cast<const float4*>(sb + (size_t)(c0 + c) * 1024 + n0 + n4 * 4);
    ldsT[n4 * 4 + 0][c] = f2bf(v.x);
    ldsT[n4 * 4 + 1][c] = f2bf(v.y);
    ldsT[n4 * 4 + 2][c] = f2bf(v.z);
    ldsT[n4 * 4 + 3][c] = f2bf(v.w);
  }
  __syncthreads();
  ushort* db = dst + ((size_t)b << 18);
  int nn = tid >> 4, c4 = tid & 15;
#pragma unroll
  for (int s = 0; s < 4; ++s) {
    int n = nn + s * 16;
    ushort4v u = *reinterpret_cast<const ushort4v*>(&ldsT[n][c4 * 4]);
    *reinterpret_cast<ushort4v*>(db + (size_t)(n0 + n) * 256 + c0 + c4 * 4) = u;
  }
}

// ---------------- kernel 1: QKV projection GEMM with fused l2norm + transpose.
// Round-6 structure (64 KB tiles, A preloaded, 8 steps) + T4 counted-vmcnt
// pipeline: prefetch loads stay in flight across raw barriers; per step we
// wait only vmcnt(8) (= tile t arrived; tile t+1's 8 loads still flying).
// flat grid 384 = 24 o-tiles x 16 b, XCD-swizzled. 512 thr = 8 waves.
// Block: 32o x 1024n (norm block-local).
__global__ __launch_bounds__(512, 2) void k_qkv(const ushort* __restrict__ wqkvb,
    const ushort* __restrict__ xbt, const ushort* __restrict__ ybt,
    ushort* __restrict__ qt, ushort* __restrict__ kt, ushort* __restrict__ vbuf) {
  int bid = blockIdx.x;
  int lid = (bid & 7) * 48 + (bid >> 3);
  int ox = lid % 24;
  int b = lid / 24;
  int o0 = ox * 32;
  const ushort* Bsrc = (o0 < 256) ? xbt : ybt;   // q from x; k,v from y
  const char* Bm = (const char*)(Bsrc + ((size_t)b << 18));   // [1024][256] bf16
  int tid = threadIdx.x;
  int l = tid & 63, w = tid >> 6;
  int r = l & 15, g = l >> 4;

  __shared__ __align__(16) char Bt[2][65536];
  __shared__ float snorm[8][32];
  __shared__ float fs[32];

  // A preload (16 global loads; drained by the first in-loop vmcnt)
  const ushort* Ab = wqkvb + (size_t)(o0 + r) * 256 + g * 8;
  short8 areg[2][8];
#pragma unroll
  for (int ks = 0; ks < 8; ++ks) {
    areg[0][ks] = ld8(Ab + ks * 32);
    areg[1][ks] = ld8(Ab + 4096 + ks * 32);
  }

  // staging geometry (512B rows, involutive 16B-slot swizzle on global src)
  int Lb = tid * 16;
  int trow = Lb >> 9;
  int goff = trow * 512 + ((Lb & 511) ^ ((trow & 7) << 4));
  int ldsw = w * 1024;

  f32x4 acc[2][8];
#pragma unroll
  for (int i = 0; i < 2; ++i)
#pragma unroll
    for (int j = 0; j < 8; ++j) acc[i][j] = (f32x4){0.f, 0.f, 0.f, 0.f};

  stage_tile(Bm, &Bt[0][0], goff, ldsw);   // tile 0 -> buf0

  int rr = w * 16 + r;
  int sw = (r & 7) << 4;
  for (int nt = 0; nt < 8; ++nt) {
    int cur = nt & 1;
    if (nt < 7) {
      stage_tile(Bm + (size_t)(nt + 1) * 65536, &Bt[cur ^ 1][0], goff, ldsw);
      asm volatile("s_waitcnt vmcnt(8)" ::: "memory");  // tile nt arrived (own slice)
    } else {
      asm volatile("s_waitcnt vmcnt(0)" ::: "memory");
    }
    __builtin_amdgcn_sched_barrier(0);
    __builtin_amdgcn_s_barrier();          // tile nt ready block-wide
    const char* Bc = &Bt[cur][0];
#pragma unroll
    for (int ks = 0; ks < 8; ++ks) {
      short8 bv = *reinterpret_cast<const short8*>(Bc + rr * 512 + ((ks * 64 + g * 16) ^ sw));
      acc[0][nt] = MFMA16(areg[0][ks], bv, acc[0][nt]);
      acc[1][nt] = MFMA16(areg[1][ks], bv, acc[1][nt]);
    }
    asm volatile("s_waitcnt lgkmcnt(0)" ::: "memory");  // LDS reads landed
    __builtin_amdgcn_sched_barrier(0);
    __builtin_amdgcn_s_barrier();          // all done reading buf[cur]
  }

  if (o0 < 512) {
    // ---- block-local row sum-of-squares (rows complete: full n in block)
    float ss[2][4];
#pragma unroll
    for (int mf = 0; mf < 2; ++mf)
#pragma unroll
      for (int reg = 0; reg < 4; ++reg) {
        float s = 0.f;
#pragma unroll
        for (int nt = 0; nt < 8; ++nt) { float v = acc[mf][nt][reg]; s += v * v; }
#pragma unroll
        for (int m = 1; m < 16; m <<= 1) s += __shfl_xor(s, m);
        ss[mf][reg] = s;
      }
    if (r == 0) {
#pragma unroll
      for (int mf = 0; mf < 2; ++mf)
#pragma unroll
        for (int reg = 0; reg < 4; ++reg)
          snorm[w][mf * 16 + g * 4 + reg] = ss[mf][reg];
    }
    __syncthreads();
    if (tid < 32) {
      float s = 0.f;
#pragma unroll
      for (int w2 = 0; w2 < 8; ++w2) s += snorm[w2][tid];
      fs[tid] = ((o0 < 256) ? 10.0f : 1.0f) / fmaxf(sqrtf(s), 1e-12f);
    }
    __syncthreads();
    float fr[2][4];
#pragma unroll
    for (int mf = 0; mf < 2; ++mf)
#pragma unroll
      for (int reg = 0; reg < 4; ++reg) fr[mf][reg] = fs[mf * 16 + g * 4 + reg];
    // ---- normalize in-register, pack 4 consecutive d, store [hb][n][64]
    int od = (o0 < 256) ? o0 : o0 - 256;      // 0..255
    int hh = od >> 6, d0 = od & 63;           // d0 in {0,32}
    ushort* dst = ((o0 < 256) ? qt : kt) + (((size_t)(b * 4 + hh)) << 16);
#pragma unroll
    for (int mf = 0; mf < 2; ++mf)
#pragma unroll
      for (int nt = 0; nt < 8; ++nt) {
        int n = nt * 128 + w * 16 + r;
        ushort4v u;
#pragma unroll
        for (int reg = 0; reg < 4; ++reg) u[reg] = f2bf(acc[mf][nt][reg] * fr[mf][reg]);
        *reinterpret_cast<ushort4v*>(dst + (size_t)n * 64 + d0 + mf * 16 + g * 4) = u;
      }
  } else {
    // ---- v: store [b][256][1024] bf16
#pragma unroll
    for (int mf = 0; mf < 2; ++mf) {
      int ob = o0 - 512 + mf * 16 + g * 4;
#pragma unroll
      for (int nt = 0; nt < 8; ++nt) {
        int n = nt * 128 + w * 16 + r;
#pragma unroll
        for (int reg = 0; reg < 4; ++reg)
          vbuf[(((size_t)b * 256 + ob + reg) << 10) + n] = f2bf(acc[mf][nt][reg]);
      }
    }
  }
}

// ---------------- kernel 2: fused attention, LDS-staged K/V (double-buffered),
// no-max softmax, unnormalized accumulate.  (unchanged — control)
__global__ __launch_bounds__(512, 4) void k_attn(const ushort* __restrict__ qt,
    const ushort* __restrict__ kt, const ushort* __restrict__ vbuf,
    ushort* __restrict__ aot) {
  int hb = blockIdx.x;            // b*4 + h
  int it = blockIdx.y;            // 0..7
  int h = hb & 3, b = hb >> 2;
  int tid = threadIdx.x;
  int l = tid & 63, w = tid >> 6;
  int r = l & 15, g = l >> 4;
  size_t ho = ((size_t)hb) << 16;
  const ushort* Q = qt + ho;      // [n][64]
  const char* Kg = (const char*)(kt + ho);                                       // [n][64]
  const char* Vg = (const char*)(vbuf + ((size_t)b << 18) + ((size_t)h << 16));  // [d][n]
  int i0 = it * 128 + w * 16;

  __shared__ __align__(16) ushort Kb[2][4096];   // 64 rows x 64 cols, XOR-swizzled
  __shared__ __align__(16) ushort Vb[2][4096];
  __shared__ __align__(16) ushort plds[8][1024]; // per-wave 16x64 P, XOR-swizzled

  int L = w * 1024 + l * 16;
  int srow = L >> 7;
  int swz = (srow & 7) << 4;
  int ksrc = L ^ swz;
  int vsrc_col = (L & 127) ^ swz;

  short8 qa[2];
#pragma unroll
  for (int ks = 0; ks < 2; ++ks)
    qa[ks] = ld8(Q + (size_t)(i0 + r) * 64 + ks * 32 + g * 8);

  f32x4 oacc[4];
  float rsum[4];
#pragma unroll
  for (int j = 0; j < 4; ++j) { oacc[j] = (f32x4){0.f, 0.f, 0.f, 0.f}; rsum[j] = 0.f; }

#define STAGE(buf, j0v) do { \
    gll16(Kg + (j0v) * 128 + ksrc, (char*)&Kb[buf][0] + w * 1024); \
    gll16(Vg + (size_t)srow * 2048 + (j0v) * 2 + vsrc_col, (char*)&Vb[buf][0] + w * 1024); \
  } while (0)

  STAGE(0, 0);
  __syncthreads();

  char* plc = (char*)plds[w];
  for (int t = 0; t < 16; ++t) {
    int cur = t & 1;
    if (t < 15) STAGE(cur ^ 1, (t + 1) * 64);
    const char* Kc = (const char*)&Kb[cur][0];
    const char* Vc = (const char*)&Vb[cur][0];
    f32x4 sacc[4];
#pragma unroll
    for (int nf = 0; nf < 4; ++nf) sacc[nf] = (f32x4){0.f, 0.f, 0.f, 0.f};
#pragma unroll
    for (int nf = 0; nf < 4; ++nf) {
      int row = nf * 16 + r;
      int sw = (row & 7) << 4;
      short8 k0 = *reinterpret_cast<const short8*>(Kc + ((row * 128 + g * 16) ^ sw));
      short8 k1 = *reinterpret_cast<const short8*>(Kc + ((row * 128 + 64 + g * 16) ^ sw));
      sacc[nf] = MFMA16(qa[0], k0, sacc[nf]);
      sacc[nf] = MFMA16(qa[1], k1, sacc[nf]);
    }
#pragma unroll
    for (int nf = 0; nf < 4; ++nf)
#pragma unroll
      for (int reg = 0; reg < 4; ++reg) {
        float p = __expf(sacc[nf][reg]);
        rsum[reg] += p;
        union { float f; unsigned u; } cv; cv.f = p;
        int row = g * 4 + reg;
        int xorv = ((row ^ (row >> 3)) & 7) << 4;
        int byteo = row * 128 + (((nf * 16 + r) * 2) ^ xorv);
        *(ushort*)(plc + byteo) = (ushort)(cv.u >> 16);
      }
    short8 pa[2];
#pragma unroll
    for (int ks = 0; ks < 2; ++ks) {
      int xorv = (r ^ (r >> 3)) & 7;
      int blk = (ks * 4 + g) ^ xorv;
      pa[ks] = *reinterpret_cast<const short8*>(plc + r * 128 + blk * 16);
    }
#pragma unroll
    for (int df = 0; df < 4; ++df) {
      int row = df * 16 + r;
      int sw = (row & 7) << 4;
#pragma unroll
      for (int ks = 0; ks < 2; ++ks) {
        short8 vf = *reinterpret_cast<const short8*>(Vc + ((row * 128 + ks * 64 + g * 16) ^ sw));
        oacc[df] = MFMA16(pa[ks], vf, oacc[df]);
      }
    }
    __syncthreads();
  }
#undef STAGE

#pragma unroll
  for (int reg = 0; reg < 4; ++reg) {
    float s = rsum[reg];
#pragma unroll
    for (int m = 1; m < 16; m <<= 1) s += __shfl_xor(s, m);
    rsum[reg] = 1.0f / s;
  }
#pragma unroll
  for (int df = 0; df < 4; ++df)
#pragma unroll
    for (int reg = 0; reg < 4; ++reg) {
      int i = i0 + g * 4 + reg;
      int d = df * 16 + r;
      float vo = oacc[df][reg] * rsum[reg];
      aot[((size_t)b << 18) + (size_t)i * 256 + h * 64 + d] = f2bf(vo);
    }
}

// ---------------- kernel 3: output projection + bias, LDS-staged B.
// Round-6 structure + T4 counted-vmcnt pipeline (same as k_qkv).
// flat grid 256 = 8 o-tiles x 2 n-halves x 16 b, XCD-swizzled. 512 thr = 8 waves.
// Block: 32o x 512n; B staged in 4 x 64 KB double-buffered tiles; A preloaded.
__global__ __launch_bounds__(512, 2) void k_out(const ushort* __restrict__ woutb,
    const ushort* __restrict__ aot, const float* __restrict__ bout,
    float* __restrict__ out) {
  int bid = blockIdx.x;
  int lid = (bid & 7) * 32 + (bid >> 3);
  int ox = lid & 7;
  int t2 = lid >> 3;
  int nb = t2 & 1;
  int b = t2 >> 1;
  int o0 = ox * 32;
  int tid = threadIdx.x, l = tid & 63, w = tid >> 6, r = l & 15, g = l >> 4;
  const char* Bm = (const char*)(aot + ((size_t)b << 18) + ((size_t)nb << 17));  // [512][256] bf16

  __shared__ __align__(16) char Bt[2][65536];

  const ushort* Ab = woutb + (size_t)(o0 + r) * 256 + g * 8;
  short8 areg[2][8];
#pragma unroll
  for (int ks = 0; ks < 8; ++ks) {
    areg[0][ks] = ld8(Ab + ks * 32);
    areg[1][ks] = ld8(Ab + 4096 + ks * 32);
  }

  int Lb = tid * 16;
  int trow = Lb >> 9;
  int goff = trow * 512 + ((Lb & 511) ^ ((trow & 7) << 4));
  int ldsw = w * 1024;

  f32x4 acc[2][4];
#pragma unroll
  for (int i = 0; i < 2; ++i)
#pragma unroll
    for (int j = 0; j < 4; ++j) acc[i][j] = (f32x4){0.f, 0.f, 0.f, 0.f};

  stage_tile(Bm, &Bt[0][0], goff, ldsw);

  int rr = w * 16 + r;
  int sw = (r & 7) << 4;
  for (int nt = 0; nt < 4; ++nt) {
    int cur = nt & 1;
    if (nt < 3) {
      stage_tile(Bm + (size_t)(nt + 1) * 65536, &Bt[cur ^ 1][0], goff, ldsw);
      asm volatile("s_waitcnt vmcnt(8)" ::: "memory");
    } else {
      asm volatile("s_waitcnt vmcnt(0)" ::: "memory");
    }
    __builtin_amdgcn_sched_barrier(0);
    __builtin_amdgcn_s_barrier();
    const char* Bc = &Bt[cur][0];
#pragma unroll
    for (int ks = 0; ks < 8; ++ks) {
      short8 bv = *reinterpret_cast<const short8*>(Bc + rr * 512 + ((ks * 64 + g * 16) ^ sw));
      acc[0][nt] = MFMA16(areg[0][ks], bv, acc[0][nt]);
      acc[1][nt] = MFMA16(areg[1][ks], bv, acc[1][nt]);
    }
    asm volatile("s_waitcnt lgkmcnt(0)" ::: "memory");
    __builtin_amdgcn_sched_barrier(0);
    __builtin_amdgcn_s_barrier();
  }

  float bias[2][4];
#pragma unroll
  for (int mf = 0; mf < 2; ++mf)
#pragma unroll
    for (int reg = 0; reg < 4; ++reg) bias[mf][reg] = bout[o0 + mf * 16 + g * 4 + reg];
#pragma unroll
  for (int mf = 0; mf < 2; ++mf)
#pragma unroll
    for (int nt = 0; nt < 4; ++nt)
#pragma unroll
      for (int reg = 0; reg < 4; ++reg) {
        size_t o = (size_t)(b * 256 + o0 + mf * 16 + g * 4 + reg);
        int n = nb * 512 + nt * 128 + w * 16 + r;
        out[(o << 10) + n] = acc[mf][nt][reg] + bias[mf][reg];
      }
}

extern "C" void kernel_launch(void* const* d_in, const int* in_sizes, int n_in,
                              void* d_out, int out_size, void* d_ws, size_t ws_size,
                              hipStream_t stream) {
  const float* x     = (const float*)d_in[0];
  const float* y     = (const float*)d_in[1];
  const float* wqkv  = (const float*)d_in[2];
  const float* wout  = (const float*)d_in[3];
  const float* bout  = (const float*)d_in[4];
  float* out = (float*)d_out;
  char* ws = (char*)d_ws;

  // Workspace (~40.6 MB). Aliases: xbt dead after k_qkv -> aot reuses it.
  ushort* xbt   = (ushort*)(ws + 0ull);          // 8 MiB
  ushort* aot   = (ushort*)(ws + 0ull);          //   (written by k_attn)
  ushort* ybt   = (ushort*)(ws + 8388608ull);    // 8 MiB
  ushort* qt    = (ushort*)(ws + 16777216ull);   // 8 MiB
  ushort* kt    = (ushort*)(ws + 25165824ull);   // 8 MiB
  ushort* vbuf  = (ushort*)(ws + 33554432ull);   // 8 MiB
  ushort* wqkvb = (ushort*)(ws + 41943040ull);   // 384 KiB
  ushort* woutb = (ushort*)(ws + 42336256ull);   // 128 KiB

  k_tcvt<<<2112, 256, 0, stream>>>(x, y, xbt, ybt, wqkv, wout, wqkvb, woutb);
  k_qkv<<<384, 512, 0, stream>>>(wqkvb, xbt, ybt, qt, kt, vbuf);
  k_attn<<<dim3(64, 8), 512, 0, stream>>>(qt, kt, vbuf, aot);
  k_out<<<256, 512, 0, stream>>>(woutb, aot, bout, out);
}

// Round 9
// 151.869 us; speedup vs baseline: 1.2187x; 1.0347x over previous
//
#include <hip/hip_runtime.h>
#include <hip/hip_bf16.h>
#include <stdint.h>

typedef __attribute__((ext_vector_type(8))) short short8;
typedef __attribute__((ext_vector_type(4))) float f32x4;
typedef __attribute__((ext_vector_type(4))) unsigned short ushort4v;

#define MFMA16(a, b, c) __builtin_amdgcn_mfma_f32_16x16x32_bf16((a), (b), (c), 0, 0, 0)

// sizes: B=16, C=256, N=1024 (32x32), HEADS=4, DHEAD=64, HID=256, OTOT=768

__device__ __forceinline__ ushort f2bf(float f) {
  union { float f; unsigned u; } x; x.f = f;
  unsigned r = x.u + 0x7FFFu + ((x.u >> 16) & 1u);
  return (ushort)(r >> 16);
}

__device__ __forceinline__ short8 ld8(const ushort* p) {
  return *reinterpret_cast<const short8*>(p);
}

// async global->LDS, 16B per lane; LDS dest = wave-uniform base + lane*16 (m104);
// global src is per-lane (m173).
__device__ __forceinline__ void gll16(const void* g, void* l) {
  __builtin_amdgcn_global_load_lds(
      reinterpret_cast<const __attribute__((address_space(1))) unsigned int*>(
          reinterpret_cast<uintptr_t>(g)),
      reinterpret_cast<__attribute__((address_space(3))) unsigned int*>(
          reinterpret_cast<uintptr_t>(l)),
      16, 0, 0);
}

// Stage one 64 KB tile (128 rows x 512 B) with involutive swizzle
// (16B-slot ^= row&7) pre-applied to the GLOBAL source; LDS stays linear.
// 512 threads x 8 calls x 16 B. goff/ldsw precomputed per-thread.
__device__ __forceinline__ void stage_tile(const char* gbase, char* ldsbase,
                                           int goff, int ldsw) {
#pragma unroll
  for (int c = 0; c < 8; ++c)
    gll16(gbase + c * 8192 + goff, ldsbase + c * 8192 + ldsw);
}

// ---------------- kernel 0: transpose+convert x,y (b,c,n)f32 -> (b,n,c)bf16,
// vectorized (float4 in, ushort4 out, transposed LDS staging).
// Tail blocks (tile >= 2048): weight conversion, float4-vectorized.
__global__ __launch_bounds__(256) void k_tcvt(const float* __restrict__ x,
    const float* __restrict__ y, ushort* __restrict__ xbt, ushort* __restrict__ ybt,
    const float* __restrict__ wqkv, const float* __restrict__ wout,
    ushort* __restrict__ wqkvb, ushort* __restrict__ woutb) {
  int tile = blockIdx.x;
  if (tile >= 2048) {   // weight-conversion blocks (64), float4 grid-stride
    const int t1 = 49152;           // 768*256/4
    const int tot = t1 + 16384;     // + 256*256/4
    for (int i = (tile - 2048) * 256 + threadIdx.x; i < tot; i += 64 * 256) {
      if (i < t1) {
        float4 v = reinterpret_cast<const float4*>(wqkv)[i];
        ushort4v u = {f2bf(v.x), f2bf(v.y), f2bf(v.z), f2bf(v.w)};
        reinterpret_cast<ushort4v*>(wqkvb)[i] = u;
      } else {
        int j = i - t1;
        float4 v = reinterpret_cast<const float4*>(wout)[j];
        ushort4v u = {f2bf(v.x), f2bf(v.y), f2bf(v.z), f2bf(v.w)};
        reinterpret_cast<ushort4v*>(woutb)[j] = u;
      }
    }
    return;
  }
  const float* src; ushort* dst;
  if (tile >= 1024) { tile -= 1024; src = y; dst = ybt; }
  else { src = x; dst = xbt; }
  int b = tile >> 6;
  int c0 = ((tile >> 4) & 3) << 6;
  int n0 = (tile & 15) << 6;
  __shared__ ushort ldsT[64][72];   // [n][c], pad to 72
  int tid = threadIdx.x;
  const float* sb = src + ((size_t)b << 18);
  int cc = tid >> 4, n4 = tid & 15;
#pragma unroll
  for (int s = 0; s < 4; ++s) {
    int c = cc + s * 16;
    float4 v = *reinterpret_cast<const float4*>(sb + (size_t)(c0 + c) * 1024 + n0 + n4 * 4);
    ldsT[n4 * 4 + 0][c] = f2bf(v.x);
    ldsT[n4 * 4 + 1][c] = f2bf(v.y);
    ldsT[n4 * 4 + 2][c] = f2bf(v.z);
    ldsT[n4 * 4 + 3][c] = f2bf(v.w);
  }
  __syncthreads();
  ushort* db = dst + ((size_t)b << 18);
  int nn = tid >> 4, c4 = tid & 15;
#pragma unroll
  for (int s = 0; s < 4; ++s) {
    int n = nn + s * 16;
    ushort4v u = *reinterpret_cast<const ushort4v*>(&ldsT[n][c4 * 4]);
    *reinterpret_cast<ushort4v*>(db + (size_t)(n0 + n) * 256 + c0 + c4 * 4) = u;
  }
}

// ---------------- kernel 1: QKV projection GEMM with fused l2norm + transpose.
// 64 KB tiles, A preloaded, 8 steps, counted-vmcnt (round-8 proven config).
// flat grid 384 = 24 o-tiles x 16 b, XCD-swizzled. 512 thr = 8 waves.
// Block: 32o x 1024n (norm block-local).
__global__ __launch_bounds__(512, 2) void k_qkv(const ushort* __restrict__ wqkvb,
    const ushort* __restrict__ xbt, const ushort* __restrict__ ybt,
    ushort* __restrict__ qt, ushort* __restrict__ kt, ushort* __restrict__ vbuf) {
  int bid = blockIdx.x;
  int lid = (bid & 7) * 48 + (bid >> 3);
  int ox = lid % 24;
  int b = lid / 24;
  int o0 = ox * 32;
  const ushort* Bsrc = (o0 < 256) ? xbt : ybt;   // q from x; k,v from y
  const char* Bm = (const char*)(Bsrc + ((size_t)b << 18));   // [1024][256] bf16
  int tid = threadIdx.x;
  int l = tid & 63, w = tid >> 6;
  int r = l & 15, g = l >> 4;

  __shared__ __align__(16) char Bt[2][65536];
  __shared__ float snorm[8][32];
  __shared__ float fs[32];

  // A preload (16 global loads; drained by the first in-loop vmcnt)
  const ushort* Ab = wqkvb + (size_t)(o0 + r) * 256 + g * 8;
  short8 areg[2][8];
#pragma unroll
  for (int ks = 0; ks < 8; ++ks) {
    areg[0][ks] = ld8(Ab + ks * 32);
    areg[1][ks] = ld8(Ab + 4096 + ks * 32);
  }

  // staging geometry (512B rows, involutive 16B-slot swizzle on global src)
  int Lb = tid * 16;
  int trow = Lb >> 9;
  int goff = trow * 512 + ((Lb & 511) ^ ((trow & 7) << 4));
  int ldsw = w * 1024;

  f32x4 acc[2][8];
#pragma unroll
  for (int i = 0; i < 2; ++i)
#pragma unroll
    for (int j = 0; j < 8; ++j) acc[i][j] = (f32x4){0.f, 0.f, 0.f, 0.f};

  stage_tile(Bm, &Bt[0][0], goff, ldsw);   // tile 0 -> buf0

  int rr = w * 16 + r;
  int sw = (r & 7) << 4;
  for (int nt = 0; nt < 8; ++nt) {
    int cur = nt & 1;
    if (nt < 7) {
      stage_tile(Bm + (size_t)(nt + 1) * 65536, &Bt[cur ^ 1][0], goff, ldsw);
      asm volatile("s_waitcnt vmcnt(8)" ::: "memory");  // tile nt arrived (own slice)
    } else {
      asm volatile("s_waitcnt vmcnt(0)" ::: "memory");
    }
    __builtin_amdgcn_sched_barrier(0);
    __builtin_amdgcn_s_barrier();          // tile nt ready block-wide
    const char* Bc = &Bt[cur][0];
#pragma unroll
    for (int ks = 0; ks < 8; ++ks) {
      short8 bv = *reinterpret_cast<const short8*>(Bc + rr * 512 + ((ks * 64 + g * 16) ^ sw));
      acc[0][nt] = MFMA16(areg[0][ks], bv, acc[0][nt]);
      acc[1][nt] = MFMA16(areg[1][ks], bv, acc[1][nt]);
    }
    asm volatile("s_waitcnt lgkmcnt(0)" ::: "memory");  // LDS reads landed
    __builtin_amdgcn_sched_barrier(0);
    __builtin_amdgcn_s_barrier();          // all done reading buf[cur]
  }

  if (o0 < 512) {
    // ---- block-local row sum-of-squares (rows complete: full n in block)
    float ss[2][4];
#pragma unroll
    for (int mf = 0; mf < 2; ++mf)
#pragma unroll
      for (int reg = 0; reg < 4; ++reg) {
        float s = 0.f;
#pragma unroll
        for (int nt = 0; nt < 8; ++nt) { float v = acc[mf][nt][reg]; s += v * v; }
#pragma unroll
        for (int m = 1; m < 16; m <<= 1) s += __shfl_xor(s, m);
        ss[mf][reg] = s;
      }
    if (r == 0) {
#pragma unroll
      for (int mf = 0; mf < 2; ++mf)
#pragma unroll
        for (int reg = 0; reg < 4; ++reg)
          snorm[w][mf * 16 + g * 4 + reg] = ss[mf][reg];
    }
    __syncthreads();
    if (tid < 32) {
      float s = 0.f;
#pragma unroll
      for (int w2 = 0; w2 < 8; ++w2) s += snorm[w2][tid];
      fs[tid] = ((o0 < 256) ? 10.0f : 1.0f) / fmaxf(sqrtf(s), 1e-12f);
    }
    __syncthreads();
    float fr[2][4];
#pragma unroll
    for (int mf = 0; mf < 2; ++mf)
#pragma unroll
      for (int reg = 0; reg < 4; ++reg) fr[mf][reg] = fs[mf * 16 + g * 4 + reg];
    // ---- normalize in-register, pack 4 consecutive d, store [hb][n][64]
    int od = (o0 < 256) ? o0 : o0 - 256;      // 0..255
    int hh = od >> 6, d0 = od & 63;           // d0 in {0,32}
    ushort* dst = ((o0 < 256) ? qt : kt) + (((size_t)(b * 4 + hh)) << 16);
#pragma unroll
    for (int mf = 0; mf < 2; ++mf)
#pragma unroll
      for (int nt = 0; nt < 8; ++nt) {
        int n = nt * 128 + w * 16 + r;
        ushort4v u;
#pragma unroll
        for (int reg = 0; reg < 4; ++reg) u[reg] = f2bf(acc[mf][nt][reg] * fr[mf][reg]);
        *reinterpret_cast<ushort4v*>(dst + (size_t)n * 64 + d0 + mf * 16 + g * 4) = u;
      }
  } else {
    // ---- v: store [b][256][1024] bf16
#pragma unroll
    for (int mf = 0; mf < 2; ++mf) {
      int ob = o0 - 512 + mf * 16 + g * 4;
#pragma unroll
      for (int nt = 0; nt < 8; ++nt) {
        int n = nt * 128 + w * 16 + r;
#pragma unroll
        for (int reg = 0; reg < 4; ++reg)
          vbuf[(((size_t)b * 256 + ob + reg) << 10) + n] = f2bf(acc[mf][nt][reg]);
      }
    }
  }
}

// ---------------- kernel 2: fused attention — TRIPLE-buffered K/V staging,
// single barrier per step, counted vmcnt (2-tile prefetch), setprio on MFMA.
// Safety: stage at step t targets buf[(t+2)%3], disjoint from buffers read at
// steps t and t+1; waves passing barrier t have consumed step t-1 ds_reads
// (MFMA data dependence), so overwriting the t-1 buffer after barrier t is safe.
// grid dim3(64 hb, 8 it): bid%8 = hb%8 -> i-tiles of 8 hb share an XCD L2.
// 512 thr = 8 waves; wave owns 16 q-rows. LDS 64 KB -> 2 blocks/CU.
__global__ __launch_bounds__(512, 4) void k_attn(const ushort* __restrict__ qt,
    const ushort* __restrict__ kt, const ushort* __restrict__ vbuf,
    ushort* __restrict__ aot) {
  int hb = blockIdx.x;            // b*4 + h
  int it = blockIdx.y;            // 0..7
  int h = hb & 3, b = hb >> 2;
  int tid = threadIdx.x;
  int l = tid & 63, w = tid >> 6;
  int r = l & 15, g = l >> 4;
  size_t ho = ((size_t)hb) << 16;
  const ushort* Q = qt + ho;      // [n][64]
  const char* Kg = (const char*)(kt + ho);                                       // [n][64]
  const char* Vg = (const char*)(vbuf + ((size_t)b << 18) + ((size_t)h << 16));  // [d][n]
  int i0 = it * 128 + w * 16;

  __shared__ __align__(16) ushort Kb[3][4096];   // 64 rows x 64 cols, XOR-swizzled
  __shared__ __align__(16) ushort Vb[3][4096];
  __shared__ __align__(16) ushort plds[8][1024]; // per-wave 16x64 P, XOR-swizzled

  int L = w * 1024 + l * 16;
  int srow = L >> 7;
  int swz = (srow & 7) << 4;
  int ksrc = L ^ swz;
  int vsrc_col = (L & 127) ^ swz;

  short8 qa[2];
#pragma unroll
  for (int ks = 0; ks < 2; ++ks)
    qa[ks] = ld8(Q + (size_t)(i0 + r) * 64 + ks * 32 + g * 8);

  f32x4 oacc[4];
  float rsum[4];
#pragma unroll
  for (int j = 0; j < 4; ++j) { oacc[j] = (f32x4){0.f, 0.f, 0.f, 0.f}; rsum[j] = 0.f; }

#define STAGE(buf, j0v) do { \
    gll16(Kg + (j0v) * 128 + ksrc, (char*)&Kb[buf][0] + w * 1024); \
    gll16(Vg + (size_t)srow * 2048 + (j0v) * 2 + vsrc_col, (char*)&Vb[buf][0] + w * 1024); \
  } while (0)

  STAGE(0, 0);
  STAGE(1, 64);

  char* plc = (char*)plds[w];
  int cur = 0;
  for (int t = 0; t < 16; ++t) {
    // wait: tile t's loads are the oldest outstanding (in-order vmcnt, m135);
    // tile t+1's 2 loads stay in flight across the barrier.
    if (t < 15) asm volatile("s_waitcnt vmcnt(2)" ::: "memory");
    else        asm volatile("s_waitcnt vmcnt(0)" ::: "memory");
    __builtin_amdgcn_sched_barrier(0);
    asm volatile("s_barrier" ::: "memory");   // tile t ready block-wide
    __builtin_amdgcn_sched_barrier(0);
    if (t < 14) {
      int nb3 = cur + 2; if (nb3 >= 3) nb3 -= 3;
      STAGE(nb3, (t + 2) * 64);               // 2-step prefetch cover
    }
    const char* Kc = (const char*)&Kb[cur][0];
    const char* Vc = (const char*)&Vb[cur][0];
    // ---- QK^T on this 64-col tile
    f32x4 sacc[4];
#pragma unroll
    for (int nf = 0; nf < 4; ++nf) sacc[nf] = (f32x4){0.f, 0.f, 0.f, 0.f};
    __builtin_amdgcn_s_setprio(1);
#pragma unroll
    for (int nf = 0; nf < 4; ++nf) {
      int row = nf * 16 + r;
      int sw = (row & 7) << 4;
      short8 k0 = *reinterpret_cast<const short8*>(Kc + ((row * 128 + g * 16) ^ sw));
      short8 k1 = *reinterpret_cast<const short8*>(Kc + ((row * 128 + 64 + g * 16) ^ sw));
      sacc[nf] = MFMA16(qa[0], k0, sacc[nf]);
      sacc[nf] = MFMA16(qa[1], k1, sacc[nf]);
    }
    __builtin_amdgcn_s_setprio(0);
    // ---- P = exp(S); row sums; P -> per-wave LDS (swizzled; bf16 truncation:
    // bias is common-mode between numerator and row-sum denominator)
#pragma unroll
    for (int nf = 0; nf < 4; ++nf)
#pragma unroll
      for (int reg = 0; reg < 4; ++reg) {
        float p = __expf(sacc[nf][reg]);
        rsum[reg] += p;
        union { float f; unsigned u; } cv; cv.f = p;
        int row = g * 4 + reg;
        int xorv = ((row ^ (row >> 3)) & 7) << 4;
        int byteo = row * 128 + (((nf * 16 + r) * 2) ^ xorv);
        *(ushort*)(plc + byteo) = (ushort)(cv.u >> 16);
      }
    short8 pa[2];
#pragma unroll
    for (int ks = 0; ks < 2; ++ks) {
      int xorv = (r ^ (r >> 3)) & 7;
      int blk = (ks * 4 + g) ^ xorv;
      pa[ks] = *reinterpret_cast<const short8*>(plc + r * 128 + blk * 16);
    }
    // ---- O += P * V^T
    __builtin_amdgcn_s_setprio(1);
#pragma unroll
    for (int df = 0; df < 4; ++df) {
      int row = df * 16 + r;
      int sw = (row & 7) << 4;
#pragma unroll
      for (int ks = 0; ks < 2; ++ks) {
        short8 vf = *reinterpret_cast<const short8*>(Vc + ((row * 128 + ks * 64 + g * 16) ^ sw));
        oacc[df] = MFMA16(pa[ks], vf, oacc[df]);
      }
    }
    __builtin_amdgcn_s_setprio(0);
    cur += 1; if (cur >= 3) cur -= 3;
  }
#undef STAGE

  // finalize: divide by row sums, store [n][hid] bf16
#pragma unroll
  for (int reg = 0; reg < 4; ++reg) {
    float s = rsum[reg];
#pragma unroll
    for (int m = 1; m < 16; m <<= 1) s += __shfl_xor(s, m);
    rsum[reg] = 1.0f / s;
  }
#pragma unroll
  for (int df = 0; df < 4; ++df)
#pragma unroll
    for (int reg = 0; reg < 4; ++reg) {
      int i = i0 + g * 4 + reg;
      int d = df * 16 + r;
      float vo = oacc[df][reg] * rsum[reg];
      aot[((size_t)b << 18) + (size_t)i * 256 + h * 64 + d] = f2bf(vo);
    }
}

// ---------------- kernel 3: output projection + bias, LDS-staged B.
// Round-8 config: 64 KB tiles + counted-vmcnt pipeline.
// flat grid 256 = 8 o-tiles x 2 n-halves x 16 b, XCD-swizzled. 512 thr = 8 waves.
// Block: 32o x 512n; B staged in 4 x 64 KB double-buffered tiles; A preloaded.
__global__ __launch_bounds__(512, 2) void k_out(const ushort* __restrict__ woutb,
    const ushort* __restrict__ aot, const float* __restrict__ bout,
    float* __restrict__ out) {
  int bid = blockIdx.x;
  int lid = (bid & 7) * 32 + (bid >> 3);
  int ox = lid & 7;
  int t2 = lid >> 3;
  int nb = t2 & 1;
  int b = t2 >> 1;
  int o0 = ox * 32;
  int tid = threadIdx.x, l = tid & 63, w = tid >> 6, r = l & 15, g = l >> 4;
  const char* Bm = (const char*)(aot + ((size_t)b << 18) + ((size_t)nb << 17));  // [512][256] bf16

  __shared__ __align__(16) char Bt[2][65536];

  const ushort* Ab = woutb + (size_t)(o0 + r) * 256 + g * 8;
  short8 areg[2][8];
#pragma unroll
  for (int ks = 0; ks < 8; ++ks) {
    areg[0][ks] = ld8(Ab + ks * 32);
    areg[1][ks] = ld8(Ab + 4096 + ks * 32);
  }

  int Lb = tid * 16;
  int trow = Lb >> 9;
  int goff = trow * 512 + ((Lb & 511) ^ ((trow & 7) << 4));
  int ldsw = w * 1024;

  f32x4 acc[2][4];
#pragma unroll
  for (int i = 0; i < 2; ++i)
#pragma unroll
    for (int j = 0; j < 4; ++j) acc[i][j] = (f32x4){0.f, 0.f, 0.f, 0.f};

  stage_tile(Bm, &Bt[0][0], goff, ldsw);

  int rr = w * 16 + r;
  int sw = (r & 7) << 4;
  for (int nt = 0; nt < 4; ++nt) {
    int cur = nt & 1;
    if (nt < 3) {
      stage_tile(Bm + (size_t)(nt + 1) * 65536, &Bt[cur ^ 1][0], goff, ldsw);
      asm volatile("s_waitcnt vmcnt(8)" ::: "memory");
    } else {
      asm volatile("s_waitcnt vmcnt(0)" ::: "memory");
    }
    __builtin_amdgcn_sched_barrier(0);
    __builtin_amdgcn_s_barrier();
    const char* Bc = &Bt[cur][0];
#pragma unroll
    for (int ks = 0; ks < 8; ++ks) {
      short8 bv = *reinterpret_cast<const short8*>(Bc + rr * 512 + ((ks * 64 + g * 16) ^ sw));
      acc[0][nt] = MFMA16(areg[0][ks], bv, acc[0][nt]);
      acc[1][nt] = MFMA16(areg[1][ks], bv, acc[1][nt]);
    }
    asm volatile("s_waitcnt lgkmcnt(0)" ::: "memory");
    __builtin_amdgcn_sched_barrier(0);
    __builtin_amdgcn_s_barrier();
  }

  float bias[2][4];
#pragma unroll
  for (int mf = 0; mf < 2; ++mf)
#pragma unroll
    for (int reg = 0; reg < 4; ++reg) bias[mf][reg] = bout[o0 + mf * 16 + g * 4 + reg];
#pragma unroll
  for (int mf = 0; mf < 2; ++mf)
#pragma unroll
    for (int nt = 0; nt < 4; ++nt)
#pragma unroll
      for (int reg = 0; reg < 4; ++reg) {
        size_t o = (size_t)(b * 256 + o0 + mf * 16 + g * 4 + reg);
        int n = nb * 512 + nt * 128 + w * 16 + r;
        out[(o << 10) + n] = acc[mf][nt][reg] + bias[mf][reg];
      }
}

extern "C" void kernel_launch(void* const* d_in, const int* in_sizes, int n_in,
                              void* d_out, int out_size, void* d_ws, size_t ws_size,
                              hipStream_t stream) {
  const float* x     = (const float*)d_in[0];
  const float* y     = (const float*)d_in[1];
  const float* wqkv  = (const float*)d_in[2];
  const float* wout  = (const float*)d_in[3];
  const float* bout  = (const float*)d_in[4];
  float* out = (float*)d_out;
  char* ws = (char*)d_ws;

  // Workspace (~40.6 MB). Aliases: xbt dead after k_qkv -> aot reuses it.
  ushort* xbt   = (ushort*)(ws + 0ull);          // 8 MiB
  ushort* aot   = (ushort*)(ws + 0ull);          //   (written by k_attn)
  ushort* ybt   = (ushort*)(ws + 8388608ull);    // 8 MiB
  ushort* qt    = (ushort*)(ws + 16777216ull);   // 8 MiB
  ushort* kt    = (ushort*)(ws + 25165824ull);   // 8 MiB
  ushort* vbuf  = (ushort*)(ws + 33554432ull);   // 8 MiB
  ushort* wqkvb = (ushort*)(ws + 41943040ull);   // 384 KiB
  ushort* woutb = (ushort*)(ws + 42336256ull);   // 128 KiB

  k_tcvt<<<2112, 256, 0, stream>>>(x, y, xbt, ybt, wqkv, wout, wqkvb, woutb);
  k_qkv<<<384, 512, 0, stream>>>(wqkvb, xbt, ybt, qt, kt, vbuf);
  k_attn<<<dim3(64, 8), 512, 0, stream>>>(qt, kt, vbuf, aot);
  k_out<<<256, 512, 0, stream>>>(woutb, aot, bout, out);
}